// Round 16
// baseline (179.479 us; speedup 1.0000x reference)
//
#include <hip/hip_runtime.h>

// Fused causal self-attention block, MI355X gfx950.
// B=2, T=2048, E=1024, H=16, D=64.
// 32x32x16 layouts (m74/m101): A[m=lane&31][k=(lane>>5)*8+j],
//   B[k=(lane>>5)*8+j][n=lane&31], C/D[col=lane&31, row=(reg&3)+8*(reg>>2)+4*(lane>>5)].
// History: R12 per-lane K/V loads FAILED (L1 transaction-bound). R13/14 16x16
//   + swizzled P (~41us). R15 1-wave blocks FAILED (1 wave/SIMD). R16 32x32
//   swapped-QK^T (50.5). R17 permlane repack + KVBLK=128 (44.5). R18
//   equalized ktmax (~41). R20 split-K (verified 172.7-173.9 total; attn
//   ~36). R21 2-qtiles/wave: null. R22/23/24 counted-vmcnt raw-barrier:
//   3x correctness failures -> family BANNED for headless iteration.
// R26 (this round): the one untested SAFE lever -- more independent barrier
//   DOMAINS per CU (R20 nulled more waves per domain; phase-locked). 2-wave
//   blocks (128 thr), 1024 blocks, KVBLK=64 dbuf (32KB LDS) -> ~4 blocks/CU,
//   each with its own __syncthreads schedule. Wave w: tq = 2t'+w, ktmax = t'
//   for BOTH waves -> every wave active every stage (zero idle). All compute
//   macros byte-identical to verified R20; only geometry/staging width
//   changed. Stride-36 epilogue kept (verified; 33 was bundled in failures).

typedef unsigned short u16;
typedef unsigned int u32;
typedef __bf16 bf8 __attribute__((ext_vector_type(8)));
typedef float f32x4 __attribute__((ext_vector_type(4)));
typedef float f32x16 __attribute__((ext_vector_type(16)));
typedef u32 u32x4v __attribute__((ext_vector_type(4)));

__device__ __forceinline__ u16 f2b(float f) {
    return __builtin_bit_cast(u16, (__bf16)f);         // RNE
}

__device__ __forceinline__ u32 pk2(float lo, float hi) {
    return (u32)f2b(lo) | ((u32)f2b(hi) << 16);
}

__device__ __forceinline__ f32x4 mfma16(bf8 a, bf8 b, f32x4 c) {
    return __builtin_amdgcn_mfma_f32_16x16x32_bf16(a, b, c, 0, 0, 0);
}

__device__ __forceinline__ f32x16 mfma32(bf8 a, bf8 b, f32x16 c) {
    return __builtin_amdgcn_mfma_f32_32x32x16_bf16(a, b, c, 0, 0, 0);
}

__device__ __forceinline__ float fexp2(float x) {
    return __builtin_amdgcn_exp2f(x);                  // v_exp_f32
}

// a' = [a.lo31, b.lo31]; b' = [a.hi31, b.hi31]  (VALU cross-half exchange)
__device__ __forceinline__ void pl32swap(u32& a, u32& b) {
    asm("v_permlane32_swap_b32 %0, %1" : "+v"(a), "+v"(b));
}

// async global->LDS, 16B per lane. LDS dest must be wave-uniform base + lane*16.
__device__ __forceinline__ void gload_lds16(const u16* g, u16* l) {
    __builtin_amdgcn_global_load_lds(
        (__attribute__((address_space(1))) void*)(g),
        (__attribute__((address_space(3))) void*)(l), 16, 0, 0);
}

// ---------------- prep: x->bf16 convert + both weight transposes ----------------
__global__ __launch_bounds__(256) void k_prep(const float* __restrict__ x,
                                              const float* __restrict__ Wa,
                                              const float* __restrict__ Wp,
                                              u16* __restrict__ Xb,
                                              u16* __restrict__ WtA,
                                              u16* __restrict__ WtP) {
    __shared__ float tile[64][65];
    int id = blockIdx.x, t = threadIdx.x;
    if (id < 4096) {                         // convert 4 floats/thread
        int i = id * 256 + t;
        float4 v = ((const float4*)x)[i];
        ushort4 o;
        o.x = f2b(v.x); o.y = f2b(v.y); o.z = f2b(v.z); o.w = f2b(v.w);
        ((ushort4*)Xb)[i] = o;
        return;
    }
    const float* in; u16* out; int N, j;
    if (id < 4864) { j = id - 4096; in = Wa; out = WtA; N = 3072; }
    else           { j = id - 4864; in = Wp; out = WtP; N = 1024; }
    int k0 = (j & 15) * 64, n0 = (j >> 4) * 64;
    int c = t & 63, r0 = t >> 6;
#pragma unroll
    for (int i = 0; i < 16; ++i) {
        int r = r0 + i * 4;
        tile[r][c] = in[(size_t)(k0 + r) * N + n0 + c];
    }
    __syncthreads();
#pragma unroll
    for (int i = 0; i < 16; ++i) {
        int r = r0 + i * 4;
        out[(size_t)(n0 + r) * 1024 + k0 + c] = f2b(tile[c][r]);
    }
}

// =====================================================================
// GEMM core v2 (unchanged from R13/14): C[128x128]/block, dbuf LDS,
// 1 barrier/K-step, XOR-swizzled images.
// =====================================================================
#define GEMM_STAGE(GA0, GA1, GB0, GB1, K, B)                                   \
    do {                                                                       \
        gload_lds16(GA0 + (K), As[B] + tid * 8);                               \
        gload_lds16(GA1 + (K), As[B] + (256 + tid) * 8);                       \
        gload_lds16(GB0 + (K), Bs[B] + tid * 8);                               \
        gload_lds16(GB1 + (K), Bs[B] + (256 + tid) * 8);                       \
    } while (0)

#define GEMM_CORE(Aptr, Bptr)                                                  \
    int tid = threadIdx.x;                                                     \
    int w = tid >> 6, lane = tid & 63, l16 = lane & 15, quad = lane >> 4;      \
    int m0 = blockIdx.x * 128, n0 = blockIdx.y * 128;                          \
    int wr = (w >> 1) * 64, wc = (w & 1) * 64;                                 \
    __shared__ u16 As[2][128 * 32];                                            \
    __shared__ u16 Bs[2][128 * 32];                                            \
    f32x4 acc[4][4];                                                           \
    _Pragma("unroll") for (int mi = 0; mi < 4; ++mi)                           \
        _Pragma("unroll") for (int ni = 0; ni < 4; ++ni)                       \
            _Pragma("unroll") for (int r = 0; r < 4; ++r) acc[mi][ni][r] = 0.f;\
    int srow0 = tid >> 2, srow1 = 64 + srow0;                                  \
    int slc = ((tid & 3) ^ ((tid >> 3) & 3)) * 8;   /* swizzled src chunk */   \
    const u16* gA0 = Aptr + (size_t)(m0 + srow0) * 1024 + slc;                 \
    const u16* gA1 = Aptr + (size_t)(m0 + srow1) * 1024 + slc;                 \
    const u16* gB0 = Bptr + (size_t)(n0 + srow0) * 1024 + slc;                 \
    const u16* gB1 = Bptr + (size_t)(n0 + srow1) * 1024 + slc;                 \
    int cq = (quad ^ ((l16 >> 1) & 3)) * 8;         /* frag phys chunk */      \
    GEMM_STAGE(gA0, gA1, gB0, gB1, 0, 0);                                      \
    for (int it = 0; it < 32; ++it) {                                          \
        int pb = it & 1;                                                       \
        __syncthreads();                  /* drains buf[pb] staging */         \
        bf8 af[4], bf[4];                                                      \
        _Pragma("unroll") for (int mi = 0; mi < 4; ++mi)                       \
            af[mi] = *(const bf8*)(As[pb] + (wr + mi * 16 + l16) * 32 + cq);   \
        _Pragma("unroll") for (int ni = 0; ni < 4; ++ni)                       \
            bf[ni] = *(const bf8*)(Bs[pb] + (wc + ni * 16 + l16) * 32 + cq);   \
        if (it < 31) GEMM_STAGE(gA0, gA1, gB0, gB1, (it + 1) * 32, pb ^ 1);    \
        _Pragma("unroll") for (int mi = 0; mi < 4; ++mi)                       \
            _Pragma("unroll") for (int ni = 0; ni < 4; ++ni)                   \
                acc[mi][ni] = mfma16(af[mi], bf[ni], acc[mi][ni]);             \
    }

// ---------------- QKV GEMM: [4096,1024] @ Wt[3072,1024] + bias ----------------
__global__ __launch_bounds__(256, 3) void k_qkv(const u16* __restrict__ Xb,
                                                const u16* __restrict__ WtA,
                                                const float* __restrict__ ba,
                                                u16* __restrict__ Qb,
                                                u16* __restrict__ Kb,
                                                u16* __restrict__ Vtb) {
    GEMM_CORE(Xb, WtA)
    int sel = n0 >> 10;                       // 0:Q 1:K 2:V (uniform per block)
    u16* dst = sel == 0 ? Qb : (sel == 1 ? Kb : Vtb);
    const float qs = 0.18033688011112042f;    // 0.125 * log2(e)
#pragma unroll
    for (int ni = 0; ni < 4; ++ni) {
        int n = n0 + wc + ni * 16 + l16;
        float bias = ba[n];
        int h = (n & 1023) >> 6;
        int d = n & 63;
#pragma unroll
        for (int mi = 0; mi < 4; ++mi)
#pragma unroll
            for (int r = 0; r < 4; ++r) {
                int m = m0 + wr + mi * 16 + quad * 4 + r;
                int bb = m >> 11, tt = m & 2047;
                float v = acc[mi][ni][r] + bias;
                size_t hb = (size_t)(bb * 16 + h);
                if (sel == 2)                             // V^T tiled
                    dst[hb * 131072 + (size_t)(tt >> 6) * 4096 + d * 64 + (tt & 63)] = f2b(v);
                else
                    dst[(hb * 2048 + tt) * 64 + d] =
                        f2b(sel == 0 ? v * qs : v);
            }
    }
}

// ---------------- proj GEMM: AO[4096,1024] @ WtP[1024,1024] + bias -> fp32 ----------------
__global__ __launch_bounds__(256, 3) void k_proj(const u16* __restrict__ AO,
                                                 const u16* __restrict__ WtP,
                                                 const float* __restrict__ bp,
                                                 float* __restrict__ out) {
    GEMM_CORE(AO, WtP)
#pragma unroll
    for (int ni = 0; ni < 4; ++ni) {
        int n = n0 + wc + ni * 16 + l16;
        float bias = bp[n];
#pragma unroll
        for (int mi = 0; mi < 4; ++mi)
#pragma unroll
            for (int r = 0; r < 4; ++r) {
                int m = m0 + wr + mi * 16 + quad * 4 + r;
                out[(size_t)m * 1024 + n] = acc[mi][ni][r] + bias;
            }
    }
}

// ---------------- flash attention (causal): 2-wave blocks, KVBLK=64 ----------------
// 1024 blocks (128 thr = 2 waves), one head per block, ~4 blocks/CU each
// with an INDEPENDENT __syncthreads domain (the R26 lever). Wave w owns
// q-tile tq = 2t' + w (t' = 0..31); ktmax = t' for both waves -> every
// wave active at every stage. nkt = t'+1 64-key stages, double-buffered
// 32KB LDS. Per stage: S^T = mfma32(K,Q^T); masked exp2 (lane-local l,
// treed sum); P^T repack via permlane32_swap; O^T += mfma32(V^T, P^T).
// Epilogue: O^T -> O transpose via SMEM (stride 36, verified), coalesced.

#define STAGE64(KT, B) do {                                                   \
    const u16* kt_ = Kh + (size_t)(KT) * 4096;                                \
    const u16* vt_ = Vh + (size_t)(KT) * 4096;                                \
    _Pragma("unroll") for (int i_ = 0; i_ < 4; ++i_) {                        \
        int ci_ = i_ * 128 + tid;            /* 0..511: 64 rows x 8 chunks */ \
        gload_lds16(kt_ + (ci_ >> 3) * 64 +                                   \
                    (((ci_ & 7) ^ ((ci_ >> 3) & 7)) * 8),                     \
                    SMEM[B][0] + ci_ * 8);                                    \
        gload_lds16(vt_ + (ci_ >> 3) * 64 +                                   \
                    (((ci_ & 7) ^ ((ci_ >> 3) & 7)) * 8),                     \
                    SMEM[B][1] + ci_ * 8);                                    \
    }                                                                         \
} while (0)

// one PV k-slice SG (keys 16*SG..+15 of the sub-tile); BFR = P^T frag (4 u32)
#define PVSTEP(SG, BFR) do {                                                  \
    bf8 va_ = *(const bf8*)(vb_ + l31 * 64 + (((2 * (SG) + h) ^ swz) * 8));   \
    bf8 vc_ = *(const bf8*)(vb_ + (32 + l31) * 64 +                           \
                            (((2 * (SG) + h) ^ swz) * 8));                    \
    bf8 pf_ = __builtin_bit_cast(bf8, BFR);                                   \
    oT0 = mfma32(va_, pf_, oT0);                                              \
    oT1 = mfma32(vc_, pf_, oT1);                                              \
} while (0)

// pack 32 S^T values -> 8 u32, exchange halves via permlane32_swap: the two
// outputs of each swap are exactly the two B-frag words (R16 BFRAGS mapping).
#define REPACK_PV(ST, SG0, SG1) do {                                          \
    u32 pk_[8];                                                               \
    _Pragma("unroll") for (int j = 0; j < 8; ++j)                             \
        pk_[j] = pk2(ST[2 * j], ST[2 * j + 1]);                               \
    pl32swap(pk_[0], pk_[2]); pl32swap(pk_[1], pk_[3]);                       \
    pl32swap(pk_[4], pk_[6]); pl32swap(pk_[5], pk_[7]);                       \
    u32x4v f0_ = {pk_[0], pk_[1], pk_[2], pk_[3]};                            \
    u32x4v f1_ = {pk_[4], pk_[5], pk_[6], pk_[7]};                            \
    PVSTEP(SG0, f0_);                                                         \
    PVSTEP(SG1, f1_);                                                         \
} while (0)

// balanced tree sum of 16 floats (no 16-deep serial chain)
#define TREE16(S)                                                             \
    (((((S)[0] + (S)[1]) + ((S)[2] + (S)[3])) +                               \
      (((S)[4] + (S)[5]) + ((S)[6] + (S)[7]))) +                              \
     ((((S)[8] + (S)[9]) + ((S)[10] + (S)[11])) +                             \
      (((S)[12] + (S)[13]) + ((S)[14] + (S)[15]))))

__global__ __launch_bounds__(128, 2) void k_attn(const u16* __restrict__ Qb,
                                                 const u16* __restrict__ Kb,
                                                 const u16* __restrict__ Vtb,
                                                 u16* __restrict__ AO) {
    // 1024 blocks; same-head blocks share id%8 (XCD L2 affinity). Longest first.
    int id = blockIdx.x;                     // 0..1023
    int bh = (id & 7) * 4 + ((id >> 3) & 3); // head-batch 0..31
    int tp = 31 - (id >> 5);                 // t' = 0..31 (longest first)
    int tid = threadIdx.x;                   // 0..127
    int w = tid >> 6, lane = tid & 63, l31 = lane & 31, h = lane >> 5;

    const u16* Qh = Qb  + (size_t)bh * 131072;
    const u16* Kh = Kb  + (size_t)bh * 131072;
    const u16* Vh = Vtb + (size_t)bh * 131072;      // V^T tiled: [kt][d][t64]

    __shared__ u16 SMEM[2][2][4096];         // [buf][K|V][8KB image] = 32KB

    int tq = 2 * tp + w;                     // q-tile; ktmax = tp for BOTH waves
    int qr = tq * 32;
    int ktmax = tp;
    int nkt = tp + 1;                        // block-uniform 64-key stages

    // Q^T fragments (B-operand): lane reads its own q-row, 4 d-slices.
    bf8 qf[4];
#pragma unroll
    for (int s = 0; s < 4; ++s)
        qf[s] = *(const bf8*)(Qh + (size_t)(qr + l31) * 64 + s * 16 + h * 8);

    float l_acc = 0.f;
    f32x16 oT0, oT1;
#pragma unroll
    for (int r = 0; r < 16; ++r) { oT0[r] = 0.f; oT1[r] = 0.f; }

    int swz = l31 & 7;                       // unified read-side XOR selector

    STAGE64(0, 0);
    for (int s = 0; s < nkt; ++s) {
        int pb = s & 1;
        __syncthreads();                     // drains buf[pb] staging
        if (s + 1 < nkt) STAGE64(s + 1, pb ^ 1);

        // every wave active at every stage (s <= ktmax always)
        const u16* kb_ = SMEM[pb][0];
        const u16* vb_ = SMEM[pb][1];
        bool diag = (s == ktmax);
        bool doK1 = !(diag && ((tq & 1) == 0));
        int kb0 = s * 64;

        // ---- QK^T: S^T = K · Q^T ----
        f32x16 sT0, sT1;
#pragma unroll
        for (int r = 0; r < 16; ++r) { sT0[r] = 0.f; sT1[r] = 0.f; }
#pragma unroll
        for (int d = 0; d < 4; ++d) {
            bf8 kf = *(const bf8*)(kb_ + l31 * 64 + (((2 * d + h) ^ swz) * 8));
            sT0 = mfma32(kf, qf[d], sT0);
        }
        if (doK1) {
#pragma unroll
            for (int d = 0; d < 4; ++d) {
                bf8 kf = *(const bf8*)(kb_ + (32 + l31) * 64 +
                                       (((2 * d + h) ^ swz) * 8));
                sT1 = mfma32(kf, qf[d], sT1);
            }
        }

        // ---- softmax (exp2, Q pre-scaled; mask only on diag tile) ----
        int qg = qr + l31;
        if (diag) {
#pragma unroll
            for (int r = 0; r < 16; ++r) {
                int krow = kb0 + (r & 3) + 8 * (r >> 2) + 4 * h;
                sT0[r] = fexp2(krow <= qg ? sT0[r] : -1e30f);
            }
            if (doK1) {
#pragma unroll
                for (int r = 0; r < 16; ++r) {
                    int krow = kb0 + 32 + (r & 3) + 8 * (r >> 2) + 4 * h;
                    sT1[r] = fexp2(krow <= qg ? sT1[r] : -1e30f);
                }
            }
        } else {
#pragma unroll
            for (int r = 0; r < 16; ++r) sT0[r] = fexp2(sT0[r]);
#pragma unroll
            for (int r = 0; r < 16; ++r) sT1[r] = fexp2(sT1[r]);
        }
        l_acc += TREE16(sT0);
        if (doK1) l_acc += TREE16(sT1);

        // ---- P^T repack (permlane32_swap) + PV ----
        REPACK_PV(sT0, 0, 1);
        if (doK1) REPACK_PV(sT1, 2, 3);
    }

    // all waves leave together (nkt uniform); barrier closes the WAR between
    // epilogue SMEM writes and the other wave's last frag reads.
    __syncthreads();

    float lsum = l_acc + __shfl_xor(l_acc, 32, 64);
    float linv = __builtin_amdgcn_rcpf(lsum);

    // ---- epilogue: normalize, transpose O^T -> O via SMEM (stride 36) ----
    u32* Ot = (u32*)&SMEM[0][0][0] + w * 1152;   // [32 q][36-pad u32]
#pragma unroll
    for (int j = 0; j < 8; ++j) {
        int col = 4 * (j >> 1) + 2 * h + (j & 1);   // d/2 within 32-block
        Ot[l31 * 36 + col]      = pk2(oT0[2 * j] * linv, oT0[2 * j + 1] * linv);
        Ot[l31 * 36 + 16 + col] = pk2(oT1[2 * j] * linv, oT1[2 * j + 1] * linv);
    }
    asm volatile("s_waitcnt lgkmcnt(0)" ::: "memory");
    __builtin_amdgcn_sched_barrier(0);       // rule #18: pin reads after fence

    int q2 = lane >> 1, half = lane & 1;
    int eb = bh >> 4, eh = bh & 15;
    size_t row = (size_t)eb * 2048 + qr + q2;
    const u32* src = Ot + q2 * 36 + half * 16;
    u32* dstg = (u32*)(AO + row * 1024 + eh * 64) + half * 16;
#pragma unroll
    for (int c = 0; c < 4; ++c)
        *(u32x4v*)(dstg + 4 * c) = *(const u32x4v*)(src + 4 * c);
}

extern "C" void kernel_launch(void* const* d_in, const int* in_sizes, int n_in,
                              void* d_out, int out_size, void* d_ws, size_t ws_size,
                              hipStream_t stream) {
    const float* x  = (const float*)d_in[0];
    const float* Wa = (const float*)d_in[1];
    const float* ba = (const float*)d_in[2];
    const float* Wp = (const float*)d_in[3];
    const float* bp = (const float*)d_in[4];
    float* out = (float*)d_out;

    char* ws = (char*)d_ws;
    const size_t MB = 1024 * 1024;
    u16* Xb  = (u16*)(ws);             // 8 MB  x as bf16   (reused as AO later)
    u16* WtA = (u16*)(ws + 8  * MB);   // 6 MB  W_attn^T bf16
    u16* WtP = (u16*)(ws + 14 * MB);   // 2 MB  W_proj^T bf16
    u16* Qb  = (u16*)(ws + 16 * MB);   // 8 MB  [B*H][T][D], pre-scaled
    u16* Kb  = (u16*)(ws + 24 * MB);   // 8 MB  [B*H][T][D]
    u16* Vtb = (u16*)(ws + 32 * MB);   // 8 MB  [B*H][32][64][64] tiled V^T
    u16* AO  = Xb;                     // alias: Xb dead after k_qkv (stream-ordered)

    k_prep<<<dim3(5120),    dim3(256), 0, stream>>>(x, Wa, Wp, Xb, WtA, WtP);
    k_qkv <<<dim3(32, 24),  dim3(256), 0, stream>>>(Xb, WtA, ba, Qb, Kb, Vtb);
    k_attn<<<dim3(1024),    dim3(128), 0, stream>>>(Qb, Kb, Vtb, AO);
    k_proj<<<dim3(32, 8),   dim3(256), 0, stream>>>(AO, WtP, bp, out);
}

// Round 17
// 166.199 us; speedup vs baseline: 1.0799x; 1.0799x over previous
//
#include <hip/hip_runtime.h>

// Fused causal self-attention block, MI355X gfx950.
// B=2, T=2048, E=1024, H=16, D=64.
// 32x32x16 layouts (m74/m101): A[m=lane&31][k=(lane>>5)*8+j],
//   B[k=(lane>>5)*8+j][n=lane&31], C/D[col=lane&31, row=(reg&3)+8*(reg>>2)+4*(lane>>5)].
// History: R13-R20 attn ladder -> verified best total 172.7-173.9 (attn ~36).
//   R21 2-qtiles/wave: null. R22/23/24 counted-vmcnt raw-barrier: 3x
//   correctness failures -> family BANNED. R26 more barrier domains/CU
//   (2-wave blocks): REGRESSED 179.5 -> attn space exhausted, reverted to R20.
// R26's profile exposed k_qkv: 56us, WRITE_SIZE 48.3MB vs 24 ideal (2x!).
//   Cause: V^T-tiled epilogue scatter = 2B/lane at 128B stride -> every bf16
//   its own 64B line -> partial-line RMW amplification on V's 8MB.
// R27 (this round): k_attn = R20 verbatim. k_qkv V-epilogue coalesced via
//   LDS round-trip: stage 128(n)x128(m) bf16 into the freed 32KB GEMM LDS
//   (add-swizzle u32 idx = n*64 + ((m/2+n)&63): write banks <=4-way, read
//   2-way free), barrier, each thread stores one contiguous 128B run (64 u16
//   along t) -> full-line writes, zero amplification. Barriers block-uniform
//   (sel per-block). As/Bs merged into GS[16384] so scratch can alias 32KB.

typedef unsigned short u16;
typedef unsigned int u32;
typedef __bf16 bf8 __attribute__((ext_vector_type(8)));
typedef float f32x4 __attribute__((ext_vector_type(4)));
typedef float f32x16 __attribute__((ext_vector_type(16)));
typedef u32 u32x4v __attribute__((ext_vector_type(4)));

__device__ __forceinline__ u16 f2b(float f) {
    return __builtin_bit_cast(u16, (__bf16)f);         // RNE
}

__device__ __forceinline__ u32 pk2(float lo, float hi) {
    return (u32)f2b(lo) | ((u32)f2b(hi) << 16);
}

__device__ __forceinline__ f32x4 mfma16(bf8 a, bf8 b, f32x4 c) {
    return __builtin_amdgcn_mfma_f32_16x16x32_bf16(a, b, c, 0, 0, 0);
}

__device__ __forceinline__ f32x16 mfma32(bf8 a, bf8 b, f32x16 c) {
    return __builtin_amdgcn_mfma_f32_32x32x16_bf16(a, b, c, 0, 0, 0);
}

__device__ __forceinline__ float fexp2(float x) {
    return __builtin_amdgcn_exp2f(x);                  // v_exp_f32
}

// a' = [a.lo31, b.lo31]; b' = [a.hi31, b.hi31]  (VALU cross-half exchange)
__device__ __forceinline__ void pl32swap(u32& a, u32& b) {
    asm("v_permlane32_swap_b32 %0, %1" : "+v"(a), "+v"(b));
}

// async global->LDS, 16B per lane. LDS dest must be wave-uniform base + lane*16.
__device__ __forceinline__ void gload_lds16(const u16* g, u16* l) {
    __builtin_amdgcn_global_load_lds(
        (__attribute__((address_space(1))) void*)(g),
        (__attribute__((address_space(3))) void*)(l), 16, 0, 0);
}

// ---------------- prep: x->bf16 convert + both weight transposes ----------------
__global__ __launch_bounds__(256) void k_prep(const float* __restrict__ x,
                                              const float* __restrict__ Wa,
                                              const float* __restrict__ Wp,
                                              u16* __restrict__ Xb,
                                              u16* __restrict__ WtA,
                                              u16* __restrict__ WtP) {
    __shared__ float tile[64][65];
    int id = blockIdx.x, t = threadIdx.x;
    if (id < 4096) {                         // convert 4 floats/thread
        int i = id * 256 + t;
        float4 v = ((const float4*)x)[i];
        ushort4 o;
        o.x = f2b(v.x); o.y = f2b(v.y); o.z = f2b(v.z); o.w = f2b(v.w);
        ((ushort4*)Xb)[i] = o;
        return;
    }
    const float* in; u16* out; int N, j;
    if (id < 4864) { j = id - 4096; in = Wa; out = WtA; N = 3072; }
    else           { j = id - 4864; in = Wp; out = WtP; N = 1024; }
    int k0 = (j & 15) * 64, n0 = (j >> 4) * 64;
    int c = t & 63, r0 = t >> 6;
#pragma unroll
    for (int i = 0; i < 16; ++i) {
        int r = r0 + i * 4;
        tile[r][c] = in[(size_t)(k0 + r) * N + n0 + c];
    }
    __syncthreads();
#pragma unroll
    for (int i = 0; i < 16; ++i) {
        int r = r0 + i * 4;
        out[(size_t)(n0 + r) * 1024 + k0 + c] = f2b(tile[c][r]);
    }
}

// =====================================================================
// GEMM core v3: as v2 (dbuf XOR-swizzled LDS, 1 barrier/K-step) but the
// two LDS images live in ONE array GS[16384] u16 (32KB) so epilogues can
// reuse the whole block as scratch. ASP(B)/BSP(B) = buffer pointers.
// =====================================================================
#define ASP(B) (GS + (B) * 4096)
#define BSP(B) (GS + 8192 + (B) * 4096)

#define GEMM_STAGE(GA0, GA1, GB0, GB1, K, B)                                   \
    do {                                                                       \
        gload_lds16(GA0 + (K), ASP(B) + tid * 8);                              \
        gload_lds16(GA1 + (K), ASP(B) + (256 + tid) * 8);                      \
        gload_lds16(GB0 + (K), BSP(B) + tid * 8);                              \
        gload_lds16(GB1 + (K), BSP(B) + (256 + tid) * 8);                      \
    } while (0)

#define GEMM_CORE(Aptr, Bptr)                                                  \
    int tid = threadIdx.x;                                                     \
    int w = tid >> 6, lane = tid & 63, l16 = lane & 15, quad = lane >> 4;      \
    int m0 = blockIdx.x * 128, n0 = blockIdx.y * 128;                          \
    int wr = (w >> 1) * 64, wc = (w & 1) * 64;                                 \
    __shared__ u16 GS[16384];                 /* As[2]|Bs[2], 32KB */          \
    f32x4 acc[4][4];                                                           \
    _Pragma("unroll") for (int mi = 0; mi < 4; ++mi)                           \
        _Pragma("unroll") for (int ni = 0; ni < 4; ++ni)                       \
            _Pragma("unroll") for (int r = 0; r < 4; ++r) acc[mi][ni][r] = 0.f;\
    int srow0 = tid >> 2, srow1 = 64 + srow0;                                  \
    int slc = ((tid & 3) ^ ((tid >> 3) & 3)) * 8;   /* swizzled src chunk */   \
    const u16* gA0 = Aptr + (size_t)(m0 + srow0) * 1024 + slc;                 \
    const u16* gA1 = Aptr + (size_t)(m0 + srow1) * 1024 + slc;                 \
    const u16* gB0 = Bptr + (size_t)(n0 + srow0) * 1024 + slc;                 \
    const u16* gB1 = Bptr + (size_t)(n0 + srow1) * 1024 + slc;                 \
    int cq = (quad ^ ((l16 >> 1) & 3)) * 8;         /* frag phys chunk */      \
    GEMM_STAGE(gA0, gA1, gB0, gB1, 0, 0);                                      \
    for (int it = 0; it < 32; ++it) {                                          \
        int pb = it & 1;                                                       \
        __syncthreads();                  /* drains buf[pb] staging */         \
        bf8 af[4], bf[4];                                                      \
        _Pragma("unroll") for (int mi = 0; mi < 4; ++mi)                       \
            af[mi] = *(const bf8*)(ASP(pb) + (wr + mi * 16 + l16) * 32 + cq);  \
        _Pragma("unroll") for (int ni = 0; ni < 4; ++ni)                       \
            bf[ni] = *(const bf8*)(BSP(pb) + (wc + ni * 16 + l16) * 32 + cq);  \
        if (it < 31) GEMM_STAGE(gA0, gA1, gB0, gB1, (it + 1) * 32, pb ^ 1);    \
        _Pragma("unroll") for (int mi = 0; mi < 4; ++mi)                       \
            _Pragma("unroll") for (int ni = 0; ni < 4; ++ni)                   \
                acc[mi][ni] = mfma16(af[mi], bf[ni], acc[mi][ni]);             \
    }

// ---------------- QKV GEMM: [4096,1024] @ Wt[3072,1024] + bias ----------------
// Q (pre-scaled) / K: direct coalesced stores. V: LDS-round-trip transpose
// so each thread writes one contiguous 128B run of the V^T tiled layout
// (kills the 2x partial-line write amplification seen in rocprof).
__global__ __launch_bounds__(256, 3) void k_qkv(const u16* __restrict__ Xb,
                                                const u16* __restrict__ WtA,
                                                const float* __restrict__ ba,
                                                u16* __restrict__ Qb,
                                                u16* __restrict__ Kb,
                                                u16* __restrict__ Vtb) {
    GEMM_CORE(Xb, WtA)
    int sel = n0 >> 10;                       // 0:Q 1:K 2:V (uniform per block)
    const float qs = 0.18033688011112042f;    // 0.125 * log2(e)
    if (sel == 2) {
        // ---- V path: acc -> swizzled LDS scratch -> coalesced V^T stores ----
        __syncthreads();                      // all frag reads done; GS free
        u32* scr = (u32*)GS;                  // [128 n][64 m-u32], add-swizzled
#pragma unroll
        for (int ni = 0; ni < 4; ++ni) {
            int nl = wc + ni * 16 + l16;      // n_local 0..127
            float bias = ba[n0 + nl];
#pragma unroll
            for (int mi = 0; mi < 4; ++mi)
#pragma unroll
                for (int r = 0; r < 4; ++r) {
                    int ml = wr + mi * 16 + quad * 4 + r;   // m_local 0..127
                    u32 idx = (u32)nl * 64 + (((ml >> 1) + nl) & 63);
                    ((u16*)scr)[idx * 2 + (ml & 1)] =
                        f2b(acc[mi][ni][r] + bias);
                }
        }
        __syncthreads();
        int row = tid >> 1, half = tid & 1;   // n_local, m-half
        int n = n0 + row;
        int d = n & 63, hh = (n & 1023) >> 6;
        size_t hb = (size_t)(m0 >> 11) * 16 + hh;
        int tt0 = m0 & 2047;                  // 128-aligned
        u32* dstp = (u32*)(Vtb + hb * 131072 +
                           (size_t)((tt0 >> 6) + half) * 4096 + d * 64);
        u32 buf[32];
#pragma unroll
        for (int i = 0; i < 32; ++i)
            buf[i] = scr[(u32)row * 64 + ((half * 32 + i + row) & 63)];
#pragma unroll
        for (int c = 0; c < 8; ++c) {
            u32x4v v4 = {buf[4 * c], buf[4 * c + 1],
                         buf[4 * c + 2], buf[4 * c + 3]};
            *(u32x4v*)(dstp + 4 * c) = v4;
        }
        return;
    }
    // ---- Q/K path (unchanged, coalesced 32B runs) ----
    u16* dst = sel == 0 ? Qb : Kb;
#pragma unroll
    for (int ni = 0; ni < 4; ++ni) {
        int n = n0 + wc + ni * 16 + l16;
        float bias = ba[n];
        int h = (n & 1023) >> 6;
        int d = n & 63;
#pragma unroll
        for (int mi = 0; mi < 4; ++mi)
#pragma unroll
            for (int r = 0; r < 4; ++r) {
                int m = m0 + wr + mi * 16 + quad * 4 + r;
                int bb = m >> 11, tt = m & 2047;
                float v = acc[mi][ni][r] + bias;
                size_t hb = (size_t)(bb * 16 + h);
                dst[(hb * 2048 + tt) * 64 + d] = f2b(sel == 0 ? v * qs : v);
            }
    }
}

// ---------------- proj GEMM: AO[4096,1024] @ WtP[1024,1024] + bias -> fp32 ----------------
__global__ __launch_bounds__(256, 3) void k_proj(const u16* __restrict__ AO,
                                                 const u16* __restrict__ WtP,
                                                 const float* __restrict__ bp,
                                                 float* __restrict__ out) {
    GEMM_CORE(AO, WtP)
#pragma unroll
    for (int ni = 0; ni < 4; ++ni) {
        int n = n0 + wc + ni * 16 + l16;
        float bias = bp[n];
#pragma unroll
        for (int mi = 0; mi < 4; ++mi)
#pragma unroll
            for (int r = 0; r < 4; ++r) {
                int m = m0 + wr + mi * 16 + quad * 4 + r;
                out[(size_t)m * 1024 + n] = acc[mi][ni][r] + bias;
            }
    }
}

// ---------------- flash attention (causal), 32x32 swapped-QK^T, SPLIT-K ----------------
// R20 verbatim (verified 172.7-173.9 total). Block = 8 waves (512 thr), one
// head. Wave w: q-tile tq = 4t + (w&3), key parity p = w>>2 -> kt === p
// (mod 2), kt <= ktmax = tq>>1. Per barrier: stage TWO 64-key tiles.
// Images swizzled phys_chunk = logical ^ (row&7); reads XOR by l31&7.
// S^T = mfma32(K,Q^T); exp2 (lane-local l, treed sum); P^T repack via
// v_permlane32_swap_b32; O^T += mfma32(V^T, P^T). Split-K combine via LDS.

#define STAGE128(KT2, B) do {                                                 \
    const u16* kt_ = Kh + (size_t)(KT2) * 8192;                               \
    const u16* vt_ = Vh + (size_t)(KT2) * 8192;                               \
    _Pragma("unroll") for (int i_ = 0; i_ < 2; ++i_) {                        \
        int ci_ = i_ * 512 + tid;            /* 0..1023: 128 rows x 8 chks */ \
        gload_lds16(kt_ + (ci_ >> 3) * 64 +                                   \
                    (((ci_ & 7) ^ ((ci_ >> 3) & 7)) * 8),                     \
                    SMEM[B][0] + ci_ * 8);                                    \
        gload_lds16(vt_ + (ci_ >> 3) * 64 +                                   \
                    (((ci_ & 7) ^ ((ci_ >> 3) & 7)) * 8),                     \
                    SMEM[B][1] + ci_ * 8);                                    \
    }                                                                         \
} while (0)

// one PV k-slice SG (keys 16*SG..+15 of the sub-tile); BFR = P^T frag (4 u32)
#define PVSTEP(SG, BFR) do {                                                  \
    bf8 va_ = *(const bf8*)(vb_ + l31 * 64 + (((2 * (SG) + h) ^ swz) * 8));   \
    bf8 vc_ = *(const bf8*)(vb_ + (32 + l31) * 64 +                           \
                            (((2 * (SG) + h) ^ swz) * 8));                    \
    bf8 pf_ = __builtin_bit_cast(bf8, BFR);                                   \
    oT0 = mfma32(va_, pf_, oT0);                                              \
    oT1 = mfma32(vc_, pf_, oT1);                                              \
} while (0)

// pack 32 S^T values -> 8 u32, exchange halves via permlane32_swap: the two
// outputs of each swap are exactly the two B-frag words (R16 BFRAGS mapping).
#define REPACK_PV(ST, SG0, SG1) do {                                          \
    u32 pk_[8];                                                               \
    _Pragma("unroll") for (int j = 0; j < 8; ++j)                             \
        pk_[j] = pk2(ST[2 * j], ST[2 * j + 1]);                               \
    pl32swap(pk_[0], pk_[2]); pl32swap(pk_[1], pk_[3]);                       \
    pl32swap(pk_[4], pk_[6]); pl32swap(pk_[5], pk_[7]);                       \
    u32x4v f0_ = {pk_[0], pk_[1], pk_[2], pk_[3]};                            \
    u32x4v f1_ = {pk_[4], pk_[5], pk_[6], pk_[7]};                            \
    PVSTEP(SG0, f0_);                                                         \
    PVSTEP(SG1, f1_);                                                         \
} while (0)

// balanced tree sum of 16 floats (no 16-deep serial chain)
#define TREE16(S)                                                             \
    (((((S)[0] + (S)[1]) + ((S)[2] + (S)[3])) +                               \
      (((S)[4] + (S)[5]) + ((S)[6] + (S)[7]))) +                              \
     ((((S)[8] + (S)[9]) + ((S)[10] + (S)[11])) +                             \
      (((S)[12] + (S)[13]) + ((S)[14] + (S)[15]))))

__global__ __launch_bounds__(512, 4) void k_attn(const u16* __restrict__ Qb,
                                                 const u16* __restrict__ Kb,
                                                 const u16* __restrict__ Vtb,
                                                 u16* __restrict__ AO) {
    // 512 blocks; same-head blocks share id%8 (XCD L2 affinity). Longest first.
    int id = blockIdx.x;                     // 0..511
    int bh = (id & 7) * 4 + ((id >> 3) & 3); // head-batch 0..31
    int t  = 15 - (id >> 5);                 // 0..15
    int tid = threadIdx.x;                   // 0..511
    int w = tid >> 6, lane = tid & 63, l31 = lane & 31, h = lane >> 5;
    int wq = w & 3, p = w >> 2;              // q-slot, key parity

    const u16* Qh = Qb  + (size_t)bh * 131072;
    const u16* Kh = Kb  + (size_t)bh * 131072;
    const u16* Vh = Vtb + (size_t)bh * 131072;      // V^T tiled: [kt][d][t64]

    __shared__ u16 SMEM[2][2][8192];         // [buf][K|V][image] = 64KB

    int tq = 4 * t + wq;                     // q-tile; equal ktmax +-1
    int qr = tq * 32;
    int ktmax = tq >> 1;                     // wave's last 64-key tile
    int nk2 = t + 1;                         // block-uniform 128-key stages

    // Q^T fragments (B-operand): lane reads its own q-row, 4 d-slices.
    bf8 qf[4];
#pragma unroll
    for (int s = 0; s < 4; ++s)
        qf[s] = *(const bf8*)(Qh + (size_t)(qr + l31) * 64 + s * 16 + h * 8);

    float l_acc = 0.f;
    f32x16 oT0, oT1;
#pragma unroll
    for (int r = 0; r < 16; ++r) { oT0[r] = 0.f; oT1[r] = 0.f; }

    int swz = l31 & 7;                       // unified read-side XOR selector

    STAGE128(0, 0);
    for (int k2 = 0; k2 < nk2; ++k2) {
        int pb = k2 & 1;
        __syncthreads();                     // drains buf[pb] staging
        if (k2 + 1 < nk2) STAGE128(k2 + 1, pb ^ 1);

        int kt = 2 * k2 + p;                 // this wave's parity sub-tile
        if (kt <= ktmax) {                   // wave-uniform
            const u16* kb_ = SMEM[pb][0] + p * 4096;
            const u16* vb_ = SMEM[pb][1] + p * 4096;
            bool diag = (kt == ktmax);
            bool doK1 = !(diag && ((tq & 1) == 0));

            // ---- QK^T: S^T = K · Q^T ----
            f32x16 sT0, sT1;
#pragma unroll
            for (int r = 0; r < 16; ++r) { sT0[r] = 0.f; sT1[r] = 0.f; }
#pragma unroll
            for (int d = 0; d < 4; ++d) {
                bf8 kf = *(const bf8*)(kb_ + l31 * 64 +
                                       (((2 * d + h) ^ swz) * 8));
                sT0 = mfma32(kf, qf[d], sT0);
            }
            if (doK1) {
#pragma unroll
                for (int d = 0; d < 4; ++d) {
                    bf8 kf = *(const bf8*)(kb_ + (32 + l31) * 64 +
                                           (((2 * d + h) ^ swz) * 8));
                    sT1 = mfma32(kf, qf[d], sT1);
                }
            }

            // ---- softmax (exp2, Q pre-scaled; mask only on diag tile) ----
            int kb0 = kt * 64, qg = qr + l31;
            if (diag) {
#pragma unroll
                for (int r = 0; r < 16; ++r) {
                    int krow = kb0 + (r & 3) + 8 * (r >> 2) + 4 * h;
                    sT0[r] = fexp2(krow <= qg ? sT0[r] : -1e30f);
                }
                if (doK1) {
#pragma unroll
                    for (int r = 0; r < 16; ++r) {
                        int krow = kb0 + 32 + (r & 3) + 8 * (r >> 2) + 4 * h;
                        sT1[r] = fexp2(krow <= qg ? sT1[r] : -1e30f);
                    }
                }
            } else {
#pragma unroll
                for (int r = 0; r < 16; ++r) sT0[r] = fexp2(sT0[r]);
#pragma unroll
                for (int r = 0; r < 16; ++r) sT1[r] = fexp2(sT1[r]);
            }
            l_acc += TREE16(sT0);
            if (doK1) l_acc += TREE16(sT1);

            // ---- P^T repack (permlane32_swap) + PV ----
            REPACK_PV(sT0, 0, 1);
            if (doK1) REPACK_PV(sT1, 2, 3);
        }
    }

    // ---- split-K combine: parity-1 -> LDS, parity-0 adds (exact) ----
    __syncthreads();                         // all KV reads done
    float* comb = (float*)&SMEM[0][0][0];    // 4*64*36 floats = 36KB
    if (p == 1) {
        float* cw = comb + (wq * 64 + lane) * 36;   // 144B stride, 16B-aligned
#pragma unroll
        for (int r = 0; r < 16; ++r) { cw[r] = oT0[r]; cw[16 + r] = oT1[r]; }
        cw[32] = l_acc;
    }
    __syncthreads();
    if (p == 1) return;                      // no barriers below

    const float* cr = comb + (wq * 64 + lane) * 36;
#pragma unroll
    for (int r = 0; r < 16; ++r) { oT0[r] += cr[r]; oT1[r] += cr[16 + r]; }
    l_acc += cr[32];

    float lsum = l_acc + __shfl_xor(l_acc, 32, 64);
    float linv = __builtin_amdgcn_rcpf(lsum);

    // ---- epilogue: normalize, transpose O^T -> O via LDS (disjoint region) ----
    u32* Ot = (u32*)&SMEM[0][0][0] + 9216 + wq * 1152;   // [32 q][36-pad u32]
#pragma unroll
    for (int j = 0; j < 8; ++j) {
        int col = 4 * (j >> 1) + 2 * h + (j & 1);   // d/2 within 32-block
        Ot[l31 * 36 + col]      = pk2(oT0[2 * j] * linv, oT0[2 * j + 1] * linv);
        Ot[l31 * 36 + 16 + col] = pk2(oT1[2 * j] * linv, oT1[2 * j + 1] * linv);
    }
    asm volatile("s_waitcnt lgkmcnt(0)" ::: "memory");
    __builtin_amdgcn_sched_barrier(0);       // rule #18: pin reads after fence

    int q2 = lane >> 1, half = lane & 1;
    int eb = bh >> 4, eh = bh & 15;
    size_t row = (size_t)eb * 2048 + qr + q2;
    const u32* src = Ot + q2 * 36 + half * 16;
    u32* dstg = (u32*)(AO + row * 1024 + eh * 64) + half * 16;
#pragma unroll
    for (int c = 0; c < 4; ++c)
        *(u32x4v*)(dstg + 4 * c) = *(const u32x4v*)(src + 4 * c);
}

extern "C" void kernel_launch(void* const* d_in, const int* in_sizes, int n_in,
                              void* d_out, int out_size, void* d_ws, size_t ws_size,
                              hipStream_t stream) {
    const float* x  = (const float*)d_in[0];
    const float* Wa = (const float*)d_in[1];
    const float* ba = (const float*)d_in[2];
    const float* Wp = (const float*)d_in[3];
    const float* bp = (const float*)d_in[4];
    float* out = (float*)d_out;

    char* ws = (char*)d_ws;
    const size_t MB = 1024 * 1024;
    u16* Xb  = (u16*)(ws);             // 8 MB  x as bf16   (reused as AO later)
    u16* WtA = (u16*)(ws + 8  * MB);   // 6 MB  W_attn^T bf16
    u16* WtP = (u16*)(ws + 14 * MB);   // 2 MB  W_proj^T bf16
    u16* Qb  = (u16*)(ws + 16 * MB);   // 8 MB  [B*H][T][D], pre-scaled
    u16* Kb  = (u16*)(ws + 24 * MB);   // 8 MB  [B*H][T][D]
    u16* Vtb = (u16*)(ws + 32 * MB);   // 8 MB  [B*H][32][64][64] tiled V^T
    u16* AO  = Xb;                     // alias: Xb dead after k_qkv (stream-ordered)

    k_prep<<<dim3(5120),    dim3(256), 0, stream>>>(x, Wa, Wp, Xb, WtA, WtP);
    k_qkv <<<dim3(32, 24),  dim3(256), 0, stream>>>(Xb, WtA, ba, Qb, Kb, Vtb);
    k_attn<<<dim3(512),     dim3(512), 0, stream>>>(Qb, Kb, Vtb, AO);
    k_proj<<<dim3(32, 8),   dim3(256), 0, stream>>>(AO, WtP, bp, out);
}